// Round 4
// baseline (3254.618 us; speedup 1.0000x reference)
//
#include <hip/hip_runtime.h>

#define D 128
#define NGRAPH 64
#define NACT 40
#define MM_ROWS 8

// ---- pool: out[g][t] += sum of feats over nodes with gids==g (gids sorted) ----
__global__ void pool_kernel(const float* __restrict__ feats, const int* __restrict__ gids,
                            float* __restrict__ out, int n_nodes, int chunk) {
    int t = threadIdx.x;                 // 0..127 column
    int start = blockIdx.x * chunk;
    int end = start + chunk;
    if (end > n_nodes) end = n_nodes;
    if (start >= end) return;
    int cur = gids[start];
    float acc = 0.f;
    for (int r = start; r < end; ++r) {
        int g = gids[r];                 // uniform across block
        if (g != cur) {
            atomicAdd(&out[cur * D + t], acc);
            acc = 0.f;
            cur = g;
        }
        acc += feats[(size_t)r * D + t];
    }
    atomicAdd(&out[cur * D + t], acc);
}

// ---- ctxgW[g] = (hg[g] + ctx[g]) @ W + b   (64 x 128, tiny) ----
__global__ void ctxw_kernel(const float* __restrict__ hg, const float* __restrict__ ctx,
                            const float* __restrict__ W, const float* __restrict__ b,
                            float* __restrict__ out) {
    __shared__ float row[D];
    int g = blockIdx.x, t = threadIdx.x;
    row[t] = hg[g * D + t] + ctx[g * D + t];
    __syncthreads();
    float acc = b[t];
#pragma unroll 4
    for (int k = 0; k < D; ++k) acc = fmaf(row[k], W[k * D + t], acc);
    out[g * D + t] = acc;
}

// ---- X = H @ W ; A = X + ctxgW[gid]  (bias+context folded in) ----
// Safe for A == H (in-place): each block reads only its own rows, and the
// __syncthreads() ensures all reads of those rows complete before any store.
__global__ void mm_kernel(const float* __restrict__ H, const float* __restrict__ W,
                          const int* __restrict__ gids, const float* __restrict__ ctxgW,
                          float* __restrict__ X, float* __restrict__ A, int n_rows) {
    int t = threadIdx.x;                 // column 0..127
    int r0 = blockIdx.x * MM_ROWS;
    float acc[MM_ROWS];
#pragma unroll
    for (int i = 0; i < MM_ROWS; ++i) acc[i] = 0.f;
#pragma unroll 4
    for (int k = 0; k < D; ++k) {
        float w = W[k * D + t];
#pragma unroll
        for (int i = 0; i < MM_ROWS; ++i) {
            int r = r0 + i;
            if (r < n_rows)              // uniform branch
                acc[i] = fmaf(H[(size_t)r * D + k], w, acc[i]);  // H load is block-uniform scalar
        }
    }
    __syncthreads();                     // all reads of this block's H rows done
#pragma unroll
    for (int i = 0; i < MM_ROWS; ++i) {
        int r = r0 + i;
        if (r < n_rows) {
            float v = acc[i];
            X[(size_t)r * D + t] = v;
            A[(size_t)r * D + t] = v + ctxgW[gids[r] * D + t];
        }
    }
}

// ---- A[dst] += X[src] over edges; 32 lanes per edge, float4 per lane ----
__global__ void scatter_kernel(const float4* __restrict__ X4, const int* __restrict__ src,
                               const int* __restrict__ dst, float* __restrict__ A, int n_edges) {
    long long gid = (long long)blockIdx.x * blockDim.x + threadIdx.x;
    int e = (int)(gid >> 5);
    if (e >= n_edges) return;
    int q = (int)(gid & 31);
    int s = src[e];
    int d0 = dst[e];
    float4 v = X4[(size_t)s * 32 + q];
    float* out = A + (size_t)d0 * D + q * 4;
    atomicAdd(out + 0, v.x);
    atomicAdd(out + 1, v.y);
    atomicAdd(out + 2, v.z);
    atomicAdd(out + 3, v.w);
}

// ---- relu in place ----
__global__ void relu_kernel(float4* __restrict__ A, int n4) {
    int stride = gridDim.x * blockDim.x;
    for (int i = blockIdx.x * blockDim.x + threadIdx.x; i < n4; i += stride) {
        float4 v = A[i];
        v.x = fmaxf(v.x, 0.f); v.y = fmaxf(v.y, 0.f);
        v.z = fmaxf(v.z, 0.f); v.w = fmaxf(v.w, 0.f);
        A[i] = v;
    }
}

// ---- head: out[g] = relu(hg[g] @ fc1W + fc1b) @ fc2W + fc2b ----
__global__ void head_kernel(const float* __restrict__ hg,
                            const float* __restrict__ fc1W, const float* __restrict__ fc1b,
                            const float* __restrict__ fc2W, const float* __restrict__ fc2b,
                            float* __restrict__ out) {
    __shared__ float row[D];
    __shared__ float hfc[D];
    int g = blockIdx.x, t = threadIdx.x;
    row[t] = hg[g * D + t];
    __syncthreads();
    float acc = fc1b[t];
#pragma unroll 4
    for (int k = 0; k < D; ++k) acc = fmaf(row[k], fc1W[k * D + t], acc);
    hfc[t] = fmaxf(acc, 0.f);
    __syncthreads();
    if (t < NACT) {
        float o = fc2b[t];
#pragma unroll 4
        for (int k = 0; k < D; ++k) o = fmaf(hfc[k], fc2W[k * NACT + t], o);
        out[g * NACT + t] = o;
    }
}

extern "C" void kernel_launch(void* const* d_in, const int* in_sizes, int n_in,
                              void* d_out, int out_size, void* d_ws, size_t ws_size,
                              hipStream_t stream) {
    const float* inputs     = (const float*)d_in[0];
    const int*   src        = (const int*)d_in[1];
    const int*   dst        = (const int*)d_in[2];
    const int*   graph_ids  = (const int*)d_in[3];
    const float* init_feats = (const float*)d_in[4];
    const int*   init_gids  = (const int*)d_in[5];
    const float* lead_feats = (const float*)d_in[6];
    const int*   lead_gids  = (const int*)d_in[7];
    const float* Wmat[3] = { (const float*)d_in[8], (const float*)d_in[10], (const float*)d_in[12] };
    const float* bvec[3] = { (const float*)d_in[9], (const float*)d_in[11], (const float*)d_in[13] };
    const float* fc1W = (const float*)d_in[14];
    const float* fc1b = (const float*)d_in[15];
    const float* fc2W = (const float*)d_in[16];
    const float* fc2b = (const float*)d_in[17];
    float* out = (float*)d_out;

    const int n_nodes = in_sizes[0] / D;
    const int n_edges = in_sizes[1];

    float* ws    = (float*)d_ws;
    float* ctx   = ws;                         // 64*128
    float* hg    = ctx + NGRAPH * D;           // 64*128
    float* ctxgW = hg + NGRAPH * D;            // 64*128
    float* X     = ctxgW + NGRAPH * D;         // n_nodes*128
    float* Ha    = X + (size_t)n_nodes * D;    // n_nodes*128  (all 3 layers in-place after L1)

    const int POOL_CHUNK = 64;
    const int pool_blocks = (n_nodes + POOL_CHUNK - 1) / POOL_CHUNK;
    const int mm_blocks = (n_nodes + MM_ROWS - 1) / MM_ROWS;
    const long long sc_threads = (long long)n_edges * 32;
    const int sc_blocks = (int)((sc_threads + 255) / 256);
    const int n4 = n_nodes * D / 4;

    // ctx = pool(init) + pool(lead)
    hipMemsetAsync(ctx, 0, NGRAPH * D * sizeof(float), stream);
    pool_kernel<<<pool_blocks, D, 0, stream>>>(init_feats, init_gids, ctx, n_nodes, POOL_CHUNK);
    pool_kernel<<<pool_blocks, D, 0, stream>>>(lead_feats, lead_gids, ctx, n_nodes, POOL_CHUNK);

    const float* Hcur = inputs;
    for (int layer = 0; layer < 3; ++layer) {
        hipMemsetAsync(hg, 0, NGRAPH * D * sizeof(float), stream);
        pool_kernel<<<pool_blocks, D, 0, stream>>>(Hcur, graph_ids, hg, n_nodes, POOL_CHUNK);
        ctxw_kernel<<<NGRAPH, D, 0, stream>>>(hg, ctx, Wmat[layer], bvec[layer], ctxgW);
        mm_kernel<<<mm_blocks, D, 0, stream>>>(Hcur, Wmat[layer], graph_ids, ctxgW, X, Ha, n_nodes);
        scatter_kernel<<<sc_blocks, 256, 0, stream>>>((const float4*)X, src, dst, Ha, n_edges);
        relu_kernel<<<2048, 256, 0, stream>>>((float4*)Ha, n4);
        Hcur = Ha;   // layers 2,3 run in-place on Ha
    }

    // final pool + head
    hipMemsetAsync(hg, 0, NGRAPH * D * sizeof(float), stream);
    pool_kernel<<<pool_blocks, D, 0, stream>>>(Hcur, graph_ids, hg, n_nodes, POOL_CHUNK);
    head_kernel<<<NGRAPH, D, 0, stream>>>(hg, fc1W, fc1b, fc2W, fc2b, out);
}

// Round 5
// 1509.347 us; speedup vs baseline: 2.1563x; 2.1563x over previous
//
#include <hip/hip_runtime.h>

#define D 128
#define NGRAPH 64
#define NACT 40
#define MM_ROWS 8

// ---- pool: out[g][t] += sum of feats over nodes with gids==g (gids sorted) ----
__global__ void pool_kernel(const float* __restrict__ feats, const int* __restrict__ gids,
                            float* __restrict__ out, int n_nodes, int chunk) {
    int t = threadIdx.x;                 // 0..127 column
    int start = blockIdx.x * chunk;
    int end = start + chunk;
    if (end > n_nodes) end = n_nodes;
    if (start >= end) return;
    int cur = gids[start];
    float acc = 0.f;
    for (int r = start; r < end; ++r) {
        int g = gids[r];                 // uniform across block
        if (g != cur) {
            atomicAdd(&out[cur * D + t], acc);
            acc = 0.f;
            cur = g;
        }
        acc += feats[(size_t)r * D + t];
    }
    atomicAdd(&out[cur * D + t], acc);
}

// ---- ctxgW[g] = (hg[g] + ctx[g]) @ W + b ----
__global__ void ctxw_kernel(const float* __restrict__ hg, const float* __restrict__ ctx,
                            const float* __restrict__ W, const float* __restrict__ b,
                            float* __restrict__ out) {
    __shared__ float row[D];
    int g = blockIdx.x, t = threadIdx.x;
    row[t] = hg[g * D + t] + ctx[g * D + t];
    __syncthreads();
    float acc = b[t];
#pragma unroll 4
    for (int k = 0; k < D; ++k) acc = fmaf(row[k], W[k * D + t], acc);
    out[g * D + t] = acc;
}

// ---- X = H @ W ----
__global__ void mm_kernel(const float* __restrict__ H, const float* __restrict__ W,
                          float* __restrict__ X, int n_rows) {
    int t = threadIdx.x;                 // column 0..127
    int r0 = blockIdx.x * MM_ROWS;
    float acc[MM_ROWS];
#pragma unroll
    for (int i = 0; i < MM_ROWS; ++i) acc[i] = 0.f;
#pragma unroll 4
    for (int k = 0; k < D; ++k) {
        float w = W[k * D + t];
#pragma unroll
        for (int i = 0; i < MM_ROWS; ++i) {
            int r = r0 + i;
            if (r < n_rows)              // uniform branch
                acc[i] = fmaf(H[(size_t)r * D + k], w, acc[i]);
        }
    }
#pragma unroll
    for (int i = 0; i < MM_ROWS; ++i) {
        int r = r0 + i;
        if (r < n_rows) X[(size_t)r * D + t] = acc[i];
    }
}

// ---- CSR build: histogram of dst ----
__global__ void hist_kernel(const int* __restrict__ dst, int* __restrict__ counts, int n_edges) {
    int stride = gridDim.x * blockDim.x;
    for (int e = blockIdx.x * blockDim.x + threadIdx.x; e < n_edges; e += stride)
        atomicAdd(&counts[dst[e]], 1);
}

// ---- CSR build: exclusive scan (single block, chunked) ----
__global__ void scan_kernel(const int* __restrict__ counts, int* __restrict__ rowptr, int n) {
    __shared__ int smem[1024];
    __shared__ int carry_s;
    int t = threadIdx.x;
    if (t == 0) { carry_s = 0; rowptr[0] = 0; }
    __syncthreads();
    for (int base = 0; base < n; base += 1024) {
        int i = base + t;
        int v = (i < n) ? counts[i] : 0;
        smem[t] = v;
        __syncthreads();
        for (int off = 1; off < 1024; off <<= 1) {
            int u = (t >= off) ? smem[t - off] : 0;
            __syncthreads();
            smem[t] += u;
            __syncthreads();
        }
        int incl = smem[t] + carry_s;
        if (i < n) rowptr[i + 1] = incl;
        __syncthreads();
        if (t == 1023) carry_s = incl;   // old carry + chunk total
        __syncthreads();
    }
}

// ---- CSR build: cursor = rowptr[0..n-1] ----
__global__ void cursor_kernel(const int* __restrict__ rowptr, int* __restrict__ cursor, int n) {
    int i = blockIdx.x * blockDim.x + threadIdx.x;
    if (i < n) cursor[i] = rowptr[i];
}

// ---- CSR build: fill srcs sorted by dst ----
__global__ void fill_kernel(const int* __restrict__ src, const int* __restrict__ dst,
                            int* __restrict__ cursor, int* __restrict__ srcs, int n_edges) {
    int stride = gridDim.x * blockDim.x;
    for (int e = blockIdx.x * blockDim.x + threadIdx.x; e < n_edges; e += stride) {
        int pos = atomicAdd(&cursor[dst[e]], 1);
        srcs[pos] = src[e];
    }
}

// ---- gather: H[n] = relu(X[n] + ctxgW[gid[n]] + sum_{e: dst==n} X[src[e]]) ----
__global__ void gather_kernel(const float* __restrict__ X, const int* __restrict__ rowptr,
                              const int* __restrict__ srcs, const int* __restrict__ gids,
                              const float* __restrict__ ctxgW, float* __restrict__ H,
                              int n_nodes) {
    int n = blockIdx.x;
    int t = threadIdx.x;
    int beg = rowptr[n], end = rowptr[n + 1];
    float acc = X[(size_t)n * D + t] + ctxgW[gids[n] * D + t];
    for (int e = beg; e < end; ++e) {
        int s = srcs[e];                 // block-uniform broadcast
        acc += X[(size_t)s * D + t];
    }
    H[(size_t)n * D + t] = fmaxf(acc, 0.f);
}

// ---- head: out[g] = relu(hg[g] @ fc1W + fc1b) @ fc2W + fc2b ----
__global__ void head_kernel(const float* __restrict__ hg,
                            const float* __restrict__ fc1W, const float* __restrict__ fc1b,
                            const float* __restrict__ fc2W, const float* __restrict__ fc2b,
                            float* __restrict__ out) {
    __shared__ float row[D];
    __shared__ float hfc[D];
    int g = blockIdx.x, t = threadIdx.x;
    row[t] = hg[g * D + t];
    __syncthreads();
    float acc = fc1b[t];
#pragma unroll 4
    for (int k = 0; k < D; ++k) acc = fmaf(row[k], fc1W[k * D + t], acc);
    hfc[t] = fmaxf(acc, 0.f);
    __syncthreads();
    if (t < NACT) {
        float o = fc2b[t];
#pragma unroll 4
        for (int k = 0; k < D; ++k) o = fmaf(hfc[k], fc2W[k * NACT + t], o);
        out[g * NACT + t] = o;
    }
}

extern "C" void kernel_launch(void* const* d_in, const int* in_sizes, int n_in,
                              void* d_out, int out_size, void* d_ws, size_t ws_size,
                              hipStream_t stream) {
    const float* inputs     = (const float*)d_in[0];
    const int*   src        = (const int*)d_in[1];
    const int*   dst        = (const int*)d_in[2];
    const int*   graph_ids  = (const int*)d_in[3];
    const float* init_feats = (const float*)d_in[4];
    const int*   init_gids  = (const int*)d_in[5];
    const float* lead_feats = (const float*)d_in[6];
    const int*   lead_gids  = (const int*)d_in[7];
    const float* Wmat[3] = { (const float*)d_in[8], (const float*)d_in[10], (const float*)d_in[12] };
    const float* bvec[3] = { (const float*)d_in[9], (const float*)d_in[11], (const float*)d_in[13] };
    const float* fc1W = (const float*)d_in[14];
    const float* fc1b = (const float*)d_in[15];
    const float* fc2W = (const float*)d_in[16];
    const float* fc2b = (const float*)d_in[17];
    float* out = (float*)d_out;

    const int n_nodes = in_sizes[0] / D;
    const int n_edges = in_sizes[1];

    float* ws    = (float*)d_ws;
    float* ctx   = ws;                           // 64*128
    float* hg    = ctx + NGRAPH * D;             // 64*128
    float* ctxgW = hg + NGRAPH * D;              // 64*128
    float* X     = ctxgW + NGRAPH * D;           // n_nodes*128
    float* Ha    = X + (size_t)n_nodes * D;      // n_nodes*128 (layers 2,3 in-place)
    int*   counts = (int*)(Ha + (size_t)n_nodes * D); // n_nodes (reused as cursor)
    int*   rowptr = counts + n_nodes;            // n_nodes+1
    int*   srcs   = rowptr + n_nodes + 1;        // n_edges

    const int POOL_CHUNK = 64;
    const int pool_blocks = (n_nodes + POOL_CHUNK - 1) / POOL_CHUNK;
    const int mm_blocks = (n_nodes + MM_ROWS - 1) / MM_ROWS;

    // ---- CSR build (once per launch, reused by all 3 layers) ----
    hipMemsetAsync(counts, 0, n_nodes * sizeof(int), stream);
    hist_kernel<<<1024, 256, 0, stream>>>(dst, counts, n_edges);
    scan_kernel<<<1, 1024, 0, stream>>>(counts, rowptr, n_nodes);
    cursor_kernel<<<(n_nodes + 255) / 256, 256, 0, stream>>>(rowptr, counts, n_nodes);
    fill_kernel<<<1024, 256, 0, stream>>>(src, dst, counts, srcs, n_edges);

    // ---- ctx = pool(init) + pool(lead) ----
    hipMemsetAsync(ctx, 0, NGRAPH * D * sizeof(float), stream);
    pool_kernel<<<pool_blocks, D, 0, stream>>>(init_feats, init_gids, ctx, n_nodes, POOL_CHUNK);
    pool_kernel<<<pool_blocks, D, 0, stream>>>(lead_feats, lead_gids, ctx, n_nodes, POOL_CHUNK);

    const float* Hcur = inputs;
    for (int layer = 0; layer < 3; ++layer) {
        hipMemsetAsync(hg, 0, NGRAPH * D * sizeof(float), stream);
        pool_kernel<<<pool_blocks, D, 0, stream>>>(Hcur, graph_ids, hg, n_nodes, POOL_CHUNK);
        ctxw_kernel<<<NGRAPH, D, 0, stream>>>(hg, ctx, Wmat[layer], bvec[layer], ctxgW);
        mm_kernel<<<mm_blocks, D, 0, stream>>>(Hcur, Wmat[layer], X, n_nodes);
        gather_kernel<<<n_nodes, D, 0, stream>>>(X, rowptr, srcs, graph_ids, ctxgW, Ha, n_nodes);
        Hcur = Ha;   // layers 2,3 in-place on Ha
    }

    // ---- final pool + head ----
    hipMemsetAsync(hg, 0, NGRAPH * D * sizeof(float), stream);
    pool_kernel<<<pool_blocks, D, 0, stream>>>(Hcur, graph_ids, hg, n_nodes, POOL_CHUNK);
    head_kernel<<<NGRAPH, D, 0, stream>>>(hg, fc1W, fc1b, fc2W, fc2b, out);
}

// Round 6
// 615.385 us; speedup vs baseline: 5.2888x; 2.4527x over previous
//
#include <hip/hip_runtime.h>

#define D 128
#define NGRAPH 64
#define NACT 40
#define BM 64
#define LDS_STRIDE 68   // 64 + 4 pad; 272 B rows: 16B-aligned, bank-clean

// ---- pool: out[g][t] += sum of feats over nodes with gids==g (gids sorted) ----
__global__ void pool_kernel(const float* __restrict__ feats, const int* __restrict__ gids,
                            float* __restrict__ out, int n_nodes, int chunk) {
    int t = threadIdx.x;                 // 0..127 column
    int start = blockIdx.x * chunk;
    int end = start + chunk;
    if (end > n_nodes) end = n_nodes;
    if (start >= end) return;
    int cur = gids[start];
    float acc = 0.f;
    int r = start;
    while (r < end) {
        if (r + 3 < end) {
            int g0 = gids[r], g3 = gids[r + 3];
            if (g0 == cur && g3 == cur) {      // common case: 4 rows, same graph
                float v0 = feats[(size_t)r * D + t];
                float v1 = feats[(size_t)(r + 1) * D + t];
                float v2 = feats[(size_t)(r + 2) * D + t];
                float v3 = feats[(size_t)(r + 3) * D + t];
                acc += (v0 + v1) + (v2 + v3);
                r += 4;
                continue;
            }
        }
        int g = gids[r];
        if (g != cur) {
            atomicAdd(&out[cur * D + t], acc);
            acc = 0.f;
            cur = g;
        }
        acc += feats[(size_t)r * D + t];
        ++r;
    }
    atomicAdd(&out[cur * D + t], acc);
}

// ---- ctxgW[g] = (hg[g] + ctx[g]) @ W + b ----
__global__ void ctxw_kernel(const float* __restrict__ hg, const float* __restrict__ ctx,
                            const float* __restrict__ W, const float* __restrict__ b,
                            float* __restrict__ out) {
    __shared__ float row[D];
    int g = blockIdx.x, t = threadIdx.x;
    row[t] = hg[g * D + t] + ctx[g * D + t];
    __syncthreads();
    float acc = b[t];
#pragma unroll 4
    for (int k = 0; k < D; ++k) acc = fmaf(row[k], W[k * D + t], acc);
    out[g * D + t] = acc;
}

// ---- X = H @ W  (LDS-tiled: BM=64 rows/block, 256 thr, 8x4 register tile) ----
__global__ __launch_bounds__(256) void mm_kernel(const float* __restrict__ H,
                                                 const float* __restrict__ W,
                                                 float* __restrict__ X, int n_rows) {
    __shared__ float hT[D * LDS_STRIDE];     // hT[k][r] = H[r0+r][k]; 34.8 KB
    int t = threadIdx.x;
    int r0 = blockIdx.x * BM;
    int tcol = t & 31;                       // cols tcol*4 .. +3
    int trow = t >> 5;                       // rows trow*8 .. +7

    // stage H[r0..r0+63][0..127] transposed; lanes vary r -> 2-way bank (free)
#pragma unroll
    for (int i = 0; i < 8; ++i) {
        int idx = t + i * 256;
        int r = idx & 63;
        int kq = idx >> 6;                   // float4 chunk along k
        int gr = r0 + r;
        float4 v = make_float4(0.f, 0.f, 0.f, 0.f);
        if (gr < n_rows) v = *(const float4*)(H + (size_t)gr * D + kq * 4);
        int k0 = kq * 4;
        hT[(k0 + 0) * LDS_STRIDE + r] = v.x;
        hT[(k0 + 1) * LDS_STRIDE + r] = v.y;
        hT[(k0 + 2) * LDS_STRIDE + r] = v.z;
        hT[(k0 + 3) * LDS_STRIDE + r] = v.w;
    }
    __syncthreads();

    float acc[8][4];
#pragma unroll
    for (int i = 0; i < 8; ++i)
#pragma unroll
        for (int j = 0; j < 4; ++j) acc[i][j] = 0.f;

#pragma unroll 4
    for (int k = 0; k < D; ++k) {
        float4 b = *(const float4*)(W + k * D + tcol * 4);   // L1-hot
        float a[8];
        *(float4*)&a[0] = *(const float4*)&hT[k * LDS_STRIDE + trow * 8];      // ds_read_b128
        *(float4*)&a[4] = *(const float4*)&hT[k * LDS_STRIDE + trow * 8 + 4];  // ds_read_b128
#pragma unroll
        for (int i = 0; i < 8; ++i) {
            acc[i][0] = fmaf(a[i], b.x, acc[i][0]);
            acc[i][1] = fmaf(a[i], b.y, acc[i][1]);
            acc[i][2] = fmaf(a[i], b.z, acc[i][2]);
            acc[i][3] = fmaf(a[i], b.w, acc[i][3]);
        }
    }

#pragma unroll
    for (int i = 0; i < 8; ++i) {
        int r = r0 + trow * 8 + i;
        if (r < n_rows) {
            float4 o = make_float4(acc[i][0], acc[i][1], acc[i][2], acc[i][3]);
            *(float4*)(X + (size_t)r * D + tcol * 4) = o;
        }
    }
}

// ---- CSR build: histogram of dst ----
__global__ void hist_kernel(const int* __restrict__ dst, int* __restrict__ counts, int n_edges) {
    int stride = gridDim.x * blockDim.x;
    for (int e = blockIdx.x * blockDim.x + threadIdx.x; e < n_edges; e += stride)
        atomicAdd(&counts[dst[e]], 1);
}

// ---- CSR build: exclusive scan (single block, 8 elems/thread) ----
__global__ void scan_kernel(const int* __restrict__ counts, int* __restrict__ rowptr, int n) {
    __shared__ int smem[1024];
    __shared__ int carry_s;
    int t = threadIdx.x;
    if (t == 0) { carry_s = 0; rowptr[0] = 0; }
    __syncthreads();
    const int CHUNK = 8192;
    for (int base = 0; base < n; base += CHUNK) {
        int i0 = base + t * 8;
        int e[8];
#pragma unroll
        for (int j = 0; j < 8; ++j) {
            int i = i0 + j;
            e[j] = (i < n) ? counts[i] : 0;
        }
#pragma unroll
        for (int j = 1; j < 8; ++j) e[j] += e[j - 1];   // inclusive within thread
        smem[t] = e[7];
        __syncthreads();
        for (int off = 1; off < 1024; off <<= 1) {
            int u = (t >= off) ? smem[t - off] : 0;
            __syncthreads();
            smem[t] += u;
            __syncthreads();
        }
        int texcl = (t ? smem[t - 1] : 0) + carry_s;
#pragma unroll
        for (int j = 0; j < 8; ++j) {
            int i = i0 + j;
            if (i < n) rowptr[i + 1] = texcl + e[j];
        }
        __syncthreads();                  // all texcl reads done before carry update
        if (t == 1023) carry_s += smem[1023];
        __syncthreads();
    }
}

// ---- CSR build: cursor = rowptr[0..n-1] ----
__global__ void cursor_kernel(const int* __restrict__ rowptr, int* __restrict__ cursor, int n) {
    int i = blockIdx.x * blockDim.x + threadIdx.x;
    if (i < n) cursor[i] = rowptr[i];
}

// ---- CSR build: fill srcs sorted by dst ----
__global__ void fill_kernel(const int* __restrict__ src, const int* __restrict__ dst,
                            int* __restrict__ cursor, int* __restrict__ srcs, int n_edges) {
    int stride = gridDim.x * blockDim.x;
    for (int e = blockIdx.x * blockDim.x + threadIdx.x; e < n_edges; e += stride) {
        int pos = atomicAdd(&cursor[dst[e]], 1);
        srcs[pos] = src[e];
    }
}

// ---- gather: H[n] = relu(X[n] + ctxgW[gid[n]] + sum_{e: dst==n} X[src[e]]) ----
__global__ void gather_kernel(const float* __restrict__ X, const int* __restrict__ rowptr,
                              const int* __restrict__ srcs, const int* __restrict__ gids,
                              const float* __restrict__ ctxgW, float* __restrict__ H,
                              int n_nodes) {
    int n = blockIdx.x;
    int t = threadIdx.x;
    int beg = rowptr[n], end = rowptr[n + 1];
    float acc = X[(size_t)n * D + t] + ctxgW[gids[n] * D + t];
    for (int e = beg; e < end; ++e) {
        int s = srcs[e];                 // block-uniform broadcast
        acc += X[(size_t)s * D + t];
    }
    H[(size_t)n * D + t] = fmaxf(acc, 0.f);
}

// ---- head: out[g] = relu(hg[g] @ fc1W + fc1b) @ fc2W + fc2b ----
__global__ void head_kernel(const float* __restrict__ hg,
                            const float* __restrict__ fc1W, const float* __restrict__ fc1b,
                            const float* __restrict__ fc2W, const float* __restrict__ fc2b,
                            float* __restrict__ out) {
    __shared__ float row[D];
    __shared__ float hfc[D];
    int g = blockIdx.x, t = threadIdx.x;
    row[t] = hg[g * D + t];
    __syncthreads();
    float acc = fc1b[t];
#pragma unroll 4
    for (int k = 0; k < D; ++k) acc = fmaf(row[k], fc1W[k * D + t], acc);
    hfc[t] = fmaxf(acc, 0.f);
    __syncthreads();
    if (t < NACT) {
        float o = fc2b[t];
#pragma unroll 4
        for (int k = 0; k < D; ++k) o = fmaf(hfc[k], fc2W[k * NACT + t], o);
        out[g * NACT + t] = o;
    }
}

extern "C" void kernel_launch(void* const* d_in, const int* in_sizes, int n_in,
                              void* d_out, int out_size, void* d_ws, size_t ws_size,
                              hipStream_t stream) {
    const float* inputs     = (const float*)d_in[0];
    const int*   src        = (const int*)d_in[1];
    const int*   dst        = (const int*)d_in[2];
    const int*   graph_ids  = (const int*)d_in[3];
    const float* init_feats = (const float*)d_in[4];
    const int*   init_gids  = (const int*)d_in[5];
    const float* lead_feats = (const float*)d_in[6];
    const int*   lead_gids  = (const int*)d_in[7];
    const float* Wmat[3] = { (const float*)d_in[8], (const float*)d_in[10], (const float*)d_in[12] };
    const float* bvec[3] = { (const float*)d_in[9], (const float*)d_in[11], (const float*)d_in[13] };
    const float* fc1W = (const float*)d_in[14];
    const float* fc1b = (const float*)d_in[15];
    const float* fc2W = (const float*)d_in[16];
    const float* fc2b = (const float*)d_in[17];
    float* out = (float*)d_out;

    const int n_nodes = in_sizes[0] / D;
    const int n_edges = in_sizes[1];

    float* ws    = (float*)d_ws;
    float* ctx   = ws;                           // 64*128
    float* hg    = ctx + NGRAPH * D;             // 64*128
    float* ctxgW = hg + NGRAPH * D;              // 64*128
    float* X     = ctxgW + NGRAPH * D;           // n_nodes*128
    float* Ha    = X + (size_t)n_nodes * D;      // n_nodes*128 (layers 2,3 in-place)
    int*   counts = (int*)(Ha + (size_t)n_nodes * D); // n_nodes (reused as cursor)
    int*   rowptr = counts + n_nodes;            // n_nodes+1
    int*   srcs   = rowptr + n_nodes + 1;        // n_edges

    const int POOL_CHUNK = 64;
    const int pool_blocks = (n_nodes + POOL_CHUNK - 1) / POOL_CHUNK;
    const int mm_blocks = (n_nodes + BM - 1) / BM;

    // ---- CSR build (once per launch, reused by all 3 layers) ----
    hipMemsetAsync(counts, 0, n_nodes * sizeof(int), stream);
    hist_kernel<<<1024, 256, 0, stream>>>(dst, counts, n_edges);
    scan_kernel<<<1, 1024, 0, stream>>>(counts, rowptr, n_nodes);
    cursor_kernel<<<(n_nodes + 255) / 256, 256, 0, stream>>>(rowptr, counts, n_nodes);
    fill_kernel<<<1024, 256, 0, stream>>>(src, dst, counts, srcs, n_edges);

    // ---- ctx = pool(init) + pool(lead) ----
    hipMemsetAsync(ctx, 0, NGRAPH * D * sizeof(float), stream);
    pool_kernel<<<pool_blocks, D, 0, stream>>>(init_feats, init_gids, ctx, n_nodes, POOL_CHUNK);
    pool_kernel<<<pool_blocks, D, 0, stream>>>(lead_feats, lead_gids, ctx, n_nodes, POOL_CHUNK);

    const float* Hcur = inputs;
    for (int layer = 0; layer < 3; ++layer) {
        hipMemsetAsync(hg, 0, NGRAPH * D * sizeof(float), stream);
        pool_kernel<<<pool_blocks, D, 0, stream>>>(Hcur, graph_ids, hg, n_nodes, POOL_CHUNK);
        ctxw_kernel<<<NGRAPH, D, 0, stream>>>(hg, ctx, Wmat[layer], bvec[layer], ctxgW);
        mm_kernel<<<mm_blocks, 256, 0, stream>>>(Hcur, Wmat[layer], X, n_nodes);
        gather_kernel<<<n_nodes, D, 0, stream>>>(X, rowptr, srcs, graph_ids, ctxgW, Ha, n_nodes);
        Hcur = Ha;   // layers 2,3 in-place on Ha
    }

    // ---- final pool + head ----
    hipMemsetAsync(hg, 0, NGRAPH * D * sizeof(float), stream);
    pool_kernel<<<pool_blocks, D, 0, stream>>>(Hcur, graph_ids, hg, n_nodes, POOL_CHUNK);
    head_kernel<<<NGRAPH, D, 0, stream>>>(hg, fc1W, fc1b, fc2W, fc2b, out);
}

// Round 7
// 514.261 us; speedup vs baseline: 6.3287x; 1.1966x over previous
//
#include <hip/hip_runtime.h>

#define D 128
#define NGRAPH 64
#define NACT 40
#define BM 64
#define LDS_STRIDE 68   // 64 + 4 pad; 272 B rows: 16B-aligned, bank-clean
#define SCAN_TPB 256
#define SCAN_EPT 8
#define SCAN_CHUNK (SCAN_TPB * SCAN_EPT)   // 2048
#define GNODES 8        // nodes per gather block (256 thr, 32 lanes/node)

// ---- pool: out[g][t] += sum of feats over nodes with gids==g (gids sorted) ----
__global__ void pool_kernel(const float* __restrict__ feats, const int* __restrict__ gids,
                            float* __restrict__ out, int n_nodes, int chunk) {
    int t = threadIdx.x;                 // 0..127 column
    int start = blockIdx.x * chunk;
    int end = start + chunk;
    if (end > n_nodes) end = n_nodes;
    if (start >= end) return;
    int cur = gids[start];
    float acc = 0.f;
    int r = start;
    while (r < end) {
        if (r + 3 < end) {
            int g0 = gids[r], g3 = gids[r + 3];
            if (g0 == cur && g3 == cur) {      // common case: 4 rows, same graph
                float v0 = feats[(size_t)r * D + t];
                float v1 = feats[(size_t)(r + 1) * D + t];
                float v2 = feats[(size_t)(r + 2) * D + t];
                float v3 = feats[(size_t)(r + 3) * D + t];
                acc += (v0 + v1) + (v2 + v3);
                r += 4;
                continue;
            }
        }
        int g = gids[r];
        if (g != cur) {
            atomicAdd(&out[cur * D + t], acc);
            acc = 0.f;
            cur = g;
        }
        acc += feats[(size_t)r * D + t];
        ++r;
    }
    atomicAdd(&out[cur * D + t], acc);
}

// ---- ctxgW[g] = (hg[g] + ctx[g]) @ W + b ----
__global__ void ctxw_kernel(const float* __restrict__ hg, const float* __restrict__ ctx,
                            const float* __restrict__ W, const float* __restrict__ b,
                            float* __restrict__ out) {
    __shared__ float row[D];
    int g = blockIdx.x, t = threadIdx.x;
    row[t] = hg[g * D + t] + ctx[g * D + t];
    __syncthreads();
    float acc = b[t];
#pragma unroll 4
    for (int k = 0; k < D; ++k) acc = fmaf(row[k], W[k * D + t], acc);
    out[g * D + t] = acc;
}

// ---- X = H @ W  (LDS-tiled: BM=64 rows/block, 256 thr, 8x4 register tile) ----
__global__ __launch_bounds__(256) void mm_kernel(const float* __restrict__ H,
                                                 const float* __restrict__ W,
                                                 float* __restrict__ X, int n_rows) {
    __shared__ float hT[D * LDS_STRIDE];     // hT[k][r] = H[r0+r][k]; 34.8 KB
    int t = threadIdx.x;
    int r0 = blockIdx.x * BM;
    int tcol = t & 31;                       // cols tcol*4 .. +3
    int trow = t >> 5;                       // rows trow*8 .. +7

#pragma unroll
    for (int i = 0; i < 8; ++i) {
        int idx = t + i * 256;
        int r = idx & 63;
        int kq = idx >> 6;                   // float4 chunk along k
        int gr = r0 + r;
        float4 v = make_float4(0.f, 0.f, 0.f, 0.f);
        if (gr < n_rows) v = *(const float4*)(H + (size_t)gr * D + kq * 4);
        int k0 = kq * 4;
        hT[(k0 + 0) * LDS_STRIDE + r] = v.x;
        hT[(k0 + 1) * LDS_STRIDE + r] = v.y;
        hT[(k0 + 2) * LDS_STRIDE + r] = v.z;
        hT[(k0 + 3) * LDS_STRIDE + r] = v.w;
    }
    __syncthreads();

    float acc[8][4];
#pragma unroll
    for (int i = 0; i < 8; ++i)
#pragma unroll
        for (int j = 0; j < 4; ++j) acc[i][j] = 0.f;

#pragma unroll 4
    for (int k = 0; k < D; ++k) {
        float4 b = *(const float4*)(W + k * D + tcol * 4);   // L1-hot
        float a[8];
        *(float4*)&a[0] = *(const float4*)&hT[k * LDS_STRIDE + trow * 8];      // ds_read_b128
        *(float4*)&a[4] = *(const float4*)&hT[k * LDS_STRIDE + trow * 8 + 4];  // ds_read_b128
#pragma unroll
        for (int i = 0; i < 8; ++i) {
            acc[i][0] = fmaf(a[i], b.x, acc[i][0]);
            acc[i][1] = fmaf(a[i], b.y, acc[i][1]);
            acc[i][2] = fmaf(a[i], b.z, acc[i][2]);
            acc[i][3] = fmaf(a[i], b.w, acc[i][3]);
        }
    }

#pragma unroll
    for (int i = 0; i < 8; ++i) {
        int r = r0 + trow * 8 + i;
        if (r < n_rows) {
            float4 o = make_float4(acc[i][0], acc[i][1], acc[i][2], acc[i][3]);
            *(float4*)(X + (size_t)r * D + tcol * 4) = o;
        }
    }
}

// ---- CSR build: histogram of dst ----
__global__ void hist_kernel(const int* __restrict__ dst, int* __restrict__ counts, int n_edges) {
    int stride = gridDim.x * blockDim.x;
    for (int e = blockIdx.x * blockDim.x + threadIdx.x; e < n_edges; e += stride)
        atomicAdd(&counts[dst[e]], 1);
}

// ---- scan phase A: per-block local inclusive scan; rowptr[i+1]=local, blocksums[b]=total ----
__global__ void scanA_kernel(const int* __restrict__ counts, int* __restrict__ rowptr,
                             int* __restrict__ blocksums, int n) {
    __shared__ int smem[SCAN_TPB];
    int b = blockIdx.x, t = threadIdx.x;
    int i0 = b * SCAN_CHUNK + t * SCAN_EPT;
    int e[SCAN_EPT];
#pragma unroll
    for (int j = 0; j < SCAN_EPT; ++j) {
        int i = i0 + j;
        e[j] = (i < n) ? counts[i] : 0;
    }
#pragma unroll
    for (int j = 1; j < SCAN_EPT; ++j) e[j] += e[j - 1];   // thread-local inclusive
    smem[t] = e[SCAN_EPT - 1];
    __syncthreads();
    for (int off = 1; off < SCAN_TPB; off <<= 1) {
        int u = (t >= off) ? smem[t - off] : 0;
        __syncthreads();
        smem[t] += u;
        __syncthreads();
    }
    int excl = t ? smem[t - 1] : 0;
#pragma unroll
    for (int j = 0; j < SCAN_EPT; ++j) {
        int i = i0 + j;
        if (i < n) rowptr[i + 1] = excl + e[j];
    }
    if (t == SCAN_TPB - 1) blocksums[b] = smem[t];
    if (b == 0 && t == 0) rowptr[0] = 0;
}

// ---- scan phase B: exclusive scan of block sums (tiny, serial) ----
__global__ void scanB_kernel(int* __restrict__ blocksums, int nb) {
    if (threadIdx.x == 0 && blockIdx.x == 0) {
        int acc = 0;
        for (int i = 0; i < nb; ++i) {
            int v = blocksums[i];
            blocksums[i] = acc;
            acc += v;
        }
    }
}

// ---- scan phase C: add block offsets; emit cursor[] = final rowptr[0..n-1] ----
__global__ void scanC_kernel(int* __restrict__ rowptr, int* __restrict__ cursor,
                             const int* __restrict__ blocksums, int n) {
    int b = blockIdx.x, t = threadIdx.x;
    int off = blocksums[b];
    int i0 = b * SCAN_CHUNK + t * SCAN_EPT;
#pragma unroll
    for (int j = 0; j < SCAN_EPT; ++j) {
        int i = i0 + j;
        if (i < n) {
            int v = rowptr[i + 1] + off;
            rowptr[i + 1] = v;
            if (i + 1 < n) cursor[i + 1] = v;
        }
    }
    if (b == 0 && t == 0) cursor[0] = 0;
}

// ---- CSR build: fill srcs sorted by dst ----
__global__ void fill_kernel(const int* __restrict__ src, const int* __restrict__ dst,
                            int* __restrict__ cursor, int* __restrict__ srcs, int n_edges) {
    int stride = gridDim.x * blockDim.x;
    for (int e = blockIdx.x * blockDim.x + threadIdx.x; e < n_edges; e += stride) {
        int pos = atomicAdd(&cursor[dst[e]], 1);
        srcs[pos] = src[e];
    }
}

// ---- gather: H[n] = relu(X[n] + ctxgW[gid[n]] + sum_{e: dst==n} X[src[e]]) ----
// 8 nodes/block, 32 lanes/node, float4/lane, 4-wide edge unroll for MLP.
__global__ __launch_bounds__(256) void gather_kernel(const float4* __restrict__ X4,
                              const int* __restrict__ rowptr, const int* __restrict__ srcs,
                              const int* __restrict__ gids, const float4* __restrict__ ctxgW4,
                              float4* __restrict__ H4, int n_nodes) {
    int n = blockIdx.x * GNODES + (threadIdx.x >> 5);
    if (n >= n_nodes) return;
    int q = threadIdx.x & 31;
    int beg = rowptr[n], end = rowptr[n + 1];
    float4 a = X4[(size_t)n * 32 + q];
    float4 c = ctxgW4[(size_t)gids[n] * 32 + q];
    float4 acc = make_float4(a.x + c.x, a.y + c.y, a.z + c.z, a.w + c.w);
    int e = beg;
    for (; e + 4 <= end; e += 4) {
        int s0 = srcs[e + 0], s1 = srcs[e + 1], s2 = srcs[e + 2], s3 = srcs[e + 3];
        float4 v0 = X4[(size_t)s0 * 32 + q];
        float4 v1 = X4[(size_t)s1 * 32 + q];
        float4 v2 = X4[(size_t)s2 * 32 + q];
        float4 v3 = X4[(size_t)s3 * 32 + q];
        acc.x += (v0.x + v1.x) + (v2.x + v3.x);
        acc.y += (v0.y + v1.y) + (v2.y + v3.y);
        acc.z += (v0.z + v1.z) + (v2.z + v3.z);
        acc.w += (v0.w + v1.w) + (v2.w + v3.w);
    }
    for (; e < end; ++e) {
        float4 v = X4[(size_t)srcs[e] * 32 + q];
        acc.x += v.x; acc.y += v.y; acc.z += v.z; acc.w += v.w;
    }
    acc.x = fmaxf(acc.x, 0.f); acc.y = fmaxf(acc.y, 0.f);
    acc.z = fmaxf(acc.z, 0.f); acc.w = fmaxf(acc.w, 0.f);
    H4[(size_t)n * 32 + q] = acc;
}

// ---- head: out[g] = relu(hg[g] @ fc1W + fc1b) @ fc2W + fc2b ----
__global__ void head_kernel(const float* __restrict__ hg,
                            const float* __restrict__ fc1W, const float* __restrict__ fc1b,
                            const float* __restrict__ fc2W, const float* __restrict__ fc2b,
                            float* __restrict__ out) {
    __shared__ float row[D];
    __shared__ float hfc[D];
    int g = blockIdx.x, t = threadIdx.x;
    row[t] = hg[g * D + t];
    __syncthreads();
    float acc = fc1b[t];
#pragma unroll 4
    for (int k = 0; k < D; ++k) acc = fmaf(row[k], fc1W[k * D + t], acc);
    hfc[t] = fmaxf(acc, 0.f);
    __syncthreads();
    if (t < NACT) {
        float o = fc2b[t];
#pragma unroll 4
        for (int k = 0; k < D; ++k) o = fmaf(hfc[k], fc2W[k * NACT + t], o);
        out[g * NACT + t] = o;
    }
}

extern "C" void kernel_launch(void* const* d_in, const int* in_sizes, int n_in,
                              void* d_out, int out_size, void* d_ws, size_t ws_size,
                              hipStream_t stream) {
    const float* inputs     = (const float*)d_in[0];
    const int*   src        = (const int*)d_in[1];
    const int*   dst        = (const int*)d_in[2];
    const int*   graph_ids  = (const int*)d_in[3];
    const float* init_feats = (const float*)d_in[4];
    const int*   init_gids  = (const int*)d_in[5];
    const float* lead_feats = (const float*)d_in[6];
    const int*   lead_gids  = (const int*)d_in[7];
    const float* Wmat[3] = { (const float*)d_in[8], (const float*)d_in[10], (const float*)d_in[12] };
    const float* bvec[3] = { (const float*)d_in[9], (const float*)d_in[11], (const float*)d_in[13] };
    const float* fc1W = (const float*)d_in[14];
    const float* fc1b = (const float*)d_in[15];
    const float* fc2W = (const float*)d_in[16];
    const float* fc2b = (const float*)d_in[17];
    float* out = (float*)d_out;

    const int n_nodes = in_sizes[0] / D;
    const int n_edges = in_sizes[1];

    float* ws    = (float*)d_ws;
    float* ctx   = ws;                           // 64*128
    float* hg    = ctx + NGRAPH * D;             // 64*128
    float* ctxgW = hg + NGRAPH * D;              // 64*128
    float* X     = ctxgW + NGRAPH * D;           // n_nodes*128
    float* Ha    = X + (size_t)n_nodes * D;      // n_nodes*128 (layers 2,3 in-place)
    int*   counts = (int*)(Ha + (size_t)n_nodes * D); // n_nodes (reused as cursor)
    int*   rowptr = counts + n_nodes;            // n_nodes+1
    int*   srcs   = rowptr + n_nodes + 1;        // n_edges
    int*   blocksums = srcs + n_edges;           // <=64

    const int POOL_CHUNK = 64;
    const int pool_blocks = (n_nodes + POOL_CHUNK - 1) / POOL_CHUNK;
    const int mm_blocks = (n_nodes + BM - 1) / BM;
    const int scan_blocks = (n_nodes + SCAN_CHUNK - 1) / SCAN_CHUNK;
    const int gather_blocks = (n_nodes + GNODES - 1) / GNODES;

    // ---- CSR build (once per launch, reused by all 3 layers) ----
    hipMemsetAsync(counts, 0, n_nodes * sizeof(int), stream);
    hist_kernel<<<1024, 256, 0, stream>>>(dst, counts, n_edges);
    scanA_kernel<<<scan_blocks, SCAN_TPB, 0, stream>>>(counts, rowptr, blocksums, n_nodes);
    scanB_kernel<<<1, 64, 0, stream>>>(blocksums, scan_blocks);
    scanC_kernel<<<scan_blocks, SCAN_TPB, 0, stream>>>(rowptr, counts, blocksums, n_nodes);
    fill_kernel<<<1024, 256, 0, stream>>>(src, dst, counts, srcs, n_edges);

    // ---- ctx = pool(init) + pool(lead) ----
    hipMemsetAsync(ctx, 0, NGRAPH * D * sizeof(float), stream);
    pool_kernel<<<pool_blocks, D, 0, stream>>>(init_feats, init_gids, ctx, n_nodes, POOL_CHUNK);
    pool_kernel<<<pool_blocks, D, 0, stream>>>(lead_feats, lead_gids, ctx, n_nodes, POOL_CHUNK);

    const float* Hcur = inputs;
    for (int layer = 0; layer < 3; ++layer) {
        hipMemsetAsync(hg, 0, NGRAPH * D * sizeof(float), stream);
        pool_kernel<<<pool_blocks, D, 0, stream>>>(Hcur, graph_ids, hg, n_nodes, POOL_CHUNK);
        ctxw_kernel<<<NGRAPH, D, 0, stream>>>(hg, ctx, Wmat[layer], bvec[layer], ctxgW);
        mm_kernel<<<mm_blocks, 256, 0, stream>>>(Hcur, Wmat[layer], X, n_nodes);
        gather_kernel<<<gather_blocks, 256, 0, stream>>>((const float4*)X, rowptr, srcs,
                                                         graph_ids, (const float4*)ctxgW,
                                                         (float4*)Ha, n_nodes);
        Hcur = Ha;   // layers 2,3 in-place on Ha
    }

    // ---- final pool + head ----
    hipMemsetAsync(hg, 0, NGRAPH * D * sizeof(float), stream);
    pool_kernel<<<pool_blocks, D, 0, stream>>>(Hcur, graph_ids, hg, n_nodes, POOL_CHUNK);
    head_kernel<<<NGRAPH, D, 0, stream>>>(hg, fc1W, fc1b, fc2W, fc2b, out);
}

// Round 8
// 416.020 us; speedup vs baseline: 7.8232x; 1.2361x over previous
//
#include <hip/hip_runtime.h>

#define D 128
#define NGRAPH 64
#define NACT 40
#define SCAN_TPB 256
#define SCAN_EPT 8
#define SCAN_CHUNK 2048
#define GNODES 8
#define POOL_CHUNK 64

typedef __attribute__((ext_vector_type(8))) short bf16x8;
typedef __attribute__((ext_vector_type(4))) float f32x4;
typedef __attribute__((ext_vector_type(8))) unsigned short us8;

__device__ inline unsigned short f2b(float f) {            // fp32 -> bf16 RNE
    unsigned u = __float_as_uint(f);
    return (unsigned short)((u + 0x7FFFu + ((u >> 16) & 1u)) >> 16);
}
__device__ inline float b2f(unsigned short h) {
    return __uint_as_float(((unsigned)h) << 16);
}

// ---- fused fp32 pools: y=0 init->ctx, y=1 lead->ctx, y=2 inputs->hg0 ----
__global__ void pool3_kernel(const float* __restrict__ f0, const int* __restrict__ g0, float* o0,
                             const float* __restrict__ f1, const int* __restrict__ g1, float* o1,
                             const float* __restrict__ f2, const int* __restrict__ g2, float* o2,
                             int n_nodes) {
    const float* feats; const int* gids; float* out;
    if (blockIdx.y == 0)      { feats = f0; gids = g0; out = o0; }
    else if (blockIdx.y == 1) { feats = f1; gids = g1; out = o1; }
    else                      { feats = f2; gids = g2; out = o2; }
    int t = threadIdx.x;
    int start = blockIdx.x * POOL_CHUNK;
    int end = start + POOL_CHUNK;
    if (end > n_nodes) end = n_nodes;
    if (start >= end) return;
    int cur = gids[start];
    float acc = 0.f;
    int r = start;
    while (r < end) {
        if (r + 3 < end && gids[r] == cur && gids[r + 3] == cur) {
            float v0 = feats[(size_t)r * D + t];
            float v1 = feats[(size_t)(r + 1) * D + t];
            float v2 = feats[(size_t)(r + 2) * D + t];
            float v3 = feats[(size_t)(r + 3) * D + t];
            acc += (v0 + v1) + (v2 + v3);
            r += 4;
            continue;
        }
        int g = gids[r];
        if (g != cur) { atomicAdd(&out[cur * D + t], acc); acc = 0.f; cur = g; }
        acc += feats[(size_t)r * D + t];
        ++r;
    }
    atomicAdd(&out[cur * D + t], acc);
}

// ---- bf16 pool (graph layers 2,3 + final) ----
__global__ void pool_b16_kernel(const unsigned short* __restrict__ feats,
                                const int* __restrict__ gids, float* __restrict__ out,
                                int n_nodes) {
    int t = threadIdx.x;
    int start = blockIdx.x * POOL_CHUNK;
    int end = start + POOL_CHUNK;
    if (end > n_nodes) end = n_nodes;
    if (start >= end) return;
    int cur = gids[start];
    float acc = 0.f;
    int r = start;
    while (r < end) {
        if (r + 3 < end && gids[r] == cur && gids[r + 3] == cur) {
            float v0 = b2f(feats[(size_t)r * D + t]);
            float v1 = b2f(feats[(size_t)(r + 1) * D + t]);
            float v2 = b2f(feats[(size_t)(r + 2) * D + t]);
            float v3 = b2f(feats[(size_t)(r + 3) * D + t]);
            acc += (v0 + v1) + (v2 + v3);
            r += 4;
            continue;
        }
        int g = gids[r];
        if (g != cur) { atomicAdd(&out[cur * D + t], acc); acc = 0.f; cur = g; }
        acc += b2f(feats[(size_t)r * D + t]);
        ++r;
    }
    atomicAdd(&out[cur * D + t], acc);
}

// ---- ctxgW[g] = (hg[g] + ctx[g]) @ W + b   (fp32, exact) ----
__global__ void ctxw_kernel(const float* __restrict__ hg, const float* __restrict__ ctx,
                            const float* __restrict__ W, const float* __restrict__ b,
                            float* __restrict__ out) {
    __shared__ float row[D];
    int g = blockIdx.x, t = threadIdx.x;
    row[t] = hg[g * D + t] + ctx[g * D + t];
    __syncthreads();
    float acc = b[t];
#pragma unroll 4
    for (int k = 0; k < D; ++k) acc = fmaf(row[k], W[k * D + t], acc);
    out[g * D + t] = acc;
}

// ---- inputs fp32 -> bf16 ----
__global__ void conv_kernel(const float4* __restrict__ in4, ushort4* __restrict__ out4, int n4) {
    int stride = gridDim.x * blockDim.x;
    for (int i = blockIdx.x * blockDim.x + threadIdx.x; i < n4; i += stride) {
        float4 v = in4[i];
        ushort4 o;
        o.x = f2b(v.x); o.y = f2b(v.y); o.z = f2b(v.z); o.w = f2b(v.w);
        out4[i] = o;
    }
}

// ---- W (fp32, KxN) -> WT (bf16, NxK), 3 layers in one dispatch ----
__global__ void wconv_kernel(const float* __restrict__ W0, const float* __restrict__ W1,
                             const float* __restrict__ W2, unsigned short* __restrict__ WTb) {
    const float* W = blockIdx.y == 0 ? W0 : (blockIdx.y == 1 ? W1 : W2);
    unsigned short* WT = WTb + blockIdx.y * (D * D);
    int idx = blockIdx.x * 256 + threadIdx.x;
    int n = idx >> 7, k = idx & 127;
    WT[n * D + k] = f2b(W[k * D + n]);
}

// ---- X = H @ W via bf16 MFMA; X bf16 out ----
// A frag: row=lane&15, k = (lane>>4)*8 + [0..7] contiguous (m92 pattern)
// B frag: col=lane&15, same k pattern, from W^T (row-major by n)
// C/D:    col=lane&15, row=(lane>>4)*4 + reg (m89 verified)
__global__ __launch_bounds__(256) void mm_mfma(const unsigned short* __restrict__ Hb,
                                               const unsigned short* __restrict__ WT,
                                               unsigned short* __restrict__ X, int n_rows) {
    __shared__ unsigned short aT[64 * 136];    // 64 rows x 128 k, +8 pad (17.4 KB)
    __shared__ unsigned short bT[128 * 136];   // 128 n x 128 k, +8 pad (34.8 KB)
    int t = threadIdx.x;
    int r0 = blockIdx.x * 64;

    for (int i = t; i < 1024; i += 256) {      // stage A: 64x128 bf16
        int r = i >> 4, kq = i & 15;
        us8 v = {0, 0, 0, 0, 0, 0, 0, 0};
        if (r0 + r < n_rows) v = *(const us8*)(Hb + (size_t)(r0 + r) * D + kq * 8);
        *(us8*)&aT[r * 136 + kq * 8] = v;
    }
    for (int i = t; i < 2048; i += 256) {      // stage B: 128x128 bf16 (W^T)
        int n = i >> 4, kq = i & 15;
        *(us8*)&bT[n * 136 + kq * 8] = *(const us8*)(WT + n * D + kq * 8);
    }
    __syncthreads();

    int lane = t & 63;
    int rbase = (t >> 6) * 16;                 // wave's 16-row strip
    int arow = lane & 15, kgrp = lane >> 4;
    f32x4 acc[8];
#pragma unroll
    for (int i = 0; i < 8; ++i) acc[i] = (f32x4){0.f, 0.f, 0.f, 0.f};

#pragma unroll
    for (int kc = 0; kc < 4; ++kc) {
        bf16x8 a = *(bf16x8*)&aT[(rbase + arow) * 136 + kc * 32 + kgrp * 8];
#pragma unroll
        for (int nt = 0; nt < 8; ++nt) {
            bf16x8 b = *(bf16x8*)&bT[(nt * 16 + arow) * 136 + kc * 32 + kgrp * 8];
            acc[nt] = __builtin_amdgcn_mfma_f32_16x16x32_bf16(a, b, acc[nt], 0, 0, 0);
        }
    }

    int rr = rbase + kgrp * 4;
#pragma unroll
    for (int nt = 0; nt < 8; ++nt) {
#pragma unroll
        for (int j = 0; j < 4; ++j) {
            int r = r0 + rr + j;
            if (r < n_rows) X[(size_t)r * D + nt * 16 + arow] = f2b(acc[nt][j]);
        }
    }
}

// ---- CSR build ----
__global__ void hist_kernel(const int* __restrict__ dst, int* __restrict__ counts, int n_edges) {
    int stride = gridDim.x * blockDim.x;
    for (int e = blockIdx.x * blockDim.x + threadIdx.x; e < n_edges; e += stride)
        atomicAdd(&counts[dst[e]], 1);
}

__global__ void scanA_kernel(const int* __restrict__ counts, int* __restrict__ rowptr,
                             int* __restrict__ blocksums, int n) {
    __shared__ int smem[SCAN_TPB];
    int b = blockIdx.x, t = threadIdx.x;
    int i0 = b * SCAN_CHUNK + t * SCAN_EPT;
    int e[SCAN_EPT];
#pragma unroll
    for (int j = 0; j < SCAN_EPT; ++j) {
        int i = i0 + j;
        e[j] = (i < n) ? counts[i] : 0;
    }
#pragma unroll
    for (int j = 1; j < SCAN_EPT; ++j) e[j] += e[j - 1];
    smem[t] = e[SCAN_EPT - 1];
    __syncthreads();
    for (int off = 1; off < SCAN_TPB; off <<= 1) {
        int u = (t >= off) ? smem[t - off] : 0;
        __syncthreads();
        smem[t] += u;
        __syncthreads();
    }
    int excl = t ? smem[t - 1] : 0;
#pragma unroll
    for (int j = 0; j < SCAN_EPT; ++j) {
        int i = i0 + j;
        if (i < n) rowptr[i + 1] = excl + e[j];
    }
    if (t == SCAN_TPB - 1) blocksums[b] = smem[t];
    if (b == 0 && t == 0) rowptr[0] = 0;
}

// adds block offsets (serial prefix of raw blocksums) + emits cursor
__global__ void scanC_kernel(int* __restrict__ rowptr, int* __restrict__ cursor,
                             const int* __restrict__ blocksums, int n) {
    __shared__ int off_s;
    int b = blockIdx.x, t = threadIdx.x;
    if (t == 0) {
        int a = 0;
        for (int i = 0; i < b; ++i) a += blocksums[i];
        off_s = a;
    }
    __syncthreads();
    int off = off_s;
    int i0 = b * SCAN_CHUNK + t * SCAN_EPT;
#pragma unroll
    for (int j = 0; j < SCAN_EPT; ++j) {
        int i = i0 + j;
        if (i < n) {
            int v = rowptr[i + 1] + off;
            rowptr[i + 1] = v;
            if (i + 1 < n) cursor[i + 1] = v;
        }
    }
    if (b == 0 && t == 0) cursor[0] = 0;
}

__global__ void fill_kernel(const int* __restrict__ src, const int* __restrict__ dst,
                            int* __restrict__ cursor, int* __restrict__ srcs, int n_edges) {
    int stride = gridDim.x * blockDim.x;
    for (int e = blockIdx.x * blockDim.x + threadIdx.x; e < n_edges; e += stride) {
        int pos = atomicAdd(&cursor[dst[e]], 1);
        srcs[pos] = src[e];
    }
}

// ---- gather: Hb[n] = bf16(relu(X[n] + ctxgW[gid[n]] + sum X[src[e]])), X bf16 ----
__global__ __launch_bounds__(256) void gather_kernel(const unsigned short* __restrict__ Xb,
        const int* __restrict__ rowptr, const int* __restrict__ srcs,
        const int* __restrict__ gids, const float4* __restrict__ ctxgW4,
        unsigned short* __restrict__ Hb, int n_nodes) {
    int n = blockIdx.x * GNODES + (threadIdx.x >> 5);
    if (n >= n_nodes) return;
    int q = threadIdx.x & 31;
    int beg = rowptr[n], end = rowptr[n + 1];
    ushort4 a = *(const ushort4*)(Xb + (size_t)n * D + q * 4);
    float4 c = ctxgW4[(size_t)gids[n] * 32 + q];
    float ax = b2f(a.x) + c.x, ay = b2f(a.y) + c.y;
    float az = b2f(a.z) + c.z, aw = b2f(a.w) + c.w;
    int e = beg;
    for (; e + 4 <= end; e += 4) {
        int s0 = srcs[e], s1 = srcs[e + 1], s2 = srcs[e + 2], s3 = srcs[e + 3];
        ushort4 v0 = *(const ushort4*)(Xb + (size_t)s0 * D + q * 4);
        ushort4 v1 = *(const ushort4*)(Xb + (size_t)s1 * D + q * 4);
        ushort4 v2 = *(const ushort4*)(Xb + (size_t)s2 * D + q * 4);
        ushort4 v3 = *(const ushort4*)(Xb + (size_t)s3 * D + q * 4);
        ax += (b2f(v0.x) + b2f(v1.x)) + (b2f(v2.x) + b2f(v3.x));
        ay += (b2f(v0.y) + b2f(v1.y)) + (b2f(v2.y) + b2f(v3.y));
        az += (b2f(v0.z) + b2f(v1.z)) + (b2f(v2.z) + b2f(v3.z));
        aw += (b2f(v0.w) + b2f(v1.w)) + (b2f(v2.w) + b2f(v3.w));
    }
    for (; e < end; ++e) {
        ushort4 v = *(const ushort4*)(Xb + (size_t)srcs[e] * D + q * 4);
        ax += b2f(v.x); ay += b2f(v.y); az += b2f(v.z); aw += b2f(v.w);
    }
    ushort4 o;
    o.x = f2b(fmaxf(ax, 0.f)); o.y = f2b(fmaxf(ay, 0.f));
    o.z = f2b(fmaxf(az, 0.f)); o.w = f2b(fmaxf(aw, 0.f));
    *(ushort4*)(Hb + (size_t)n * D + q * 4) = o;
}

// ---- head ----
__global__ void head_kernel(const float* __restrict__ hg,
                            const float* __restrict__ fc1W, const float* __restrict__ fc1b,
                            const float* __restrict__ fc2W, const float* __restrict__ fc2b,
                            float* __restrict__ out) {
    __shared__ float row[D];
    __shared__ float hfc[D];
    int g = blockIdx.x, t = threadIdx.x;
    row[t] = hg[g * D + t];
    __syncthreads();
    float acc = fc1b[t];
#pragma unroll 4
    for (int k = 0; k < D; ++k) acc = fmaf(row[k], fc1W[k * D + t], acc);
    hfc[t] = fmaxf(acc, 0.f);
    __syncthreads();
    if (t < NACT) {
        float o = fc2b[t];
#pragma unroll 4
        for (int k = 0; k < D; ++k) o = fmaf(hfc[k], fc2W[k * NACT + t], o);
        out[g * NACT + t] = o;
    }
}

extern "C" void kernel_launch(void* const* d_in, const int* in_sizes, int n_in,
                              void* d_out, int out_size, void* d_ws, size_t ws_size,
                              hipStream_t stream) {
    const float* inputs     = (const float*)d_in[0];
    const int*   src        = (const int*)d_in[1];
    const int*   dst        = (const int*)d_in[2];
    const int*   graph_ids  = (const int*)d_in[3];
    const float* init_feats = (const float*)d_in[4];
    const int*   init_gids  = (const int*)d_in[5];
    const float* lead_feats = (const float*)d_in[6];
    const int*   lead_gids  = (const int*)d_in[7];
    const float* Wmat[3] = { (const float*)d_in[8], (const float*)d_in[10], (const float*)d_in[12] };
    const float* bvec[3] = { (const float*)d_in[9], (const float*)d_in[11], (const float*)d_in[13] };
    const float* fc1W = (const float*)d_in[14];
    const float* fc1b = (const float*)d_in[15];
    const float* fc2W = (const float*)d_in[16];
    const float* fc2b = (const float*)d_in[17];
    float* out = (float*)d_out;

    const int n_nodes = in_sizes[0] / D;
    const int n_edges = in_sizes[1];

    // ---- workspace layout (zero region first, then 16B-aligned bf16 blocks) ----
    unsigned char* p = (unsigned char*)d_ws;
    float* ctx    = (float*)p;                          p += NGRAPH * D * sizeof(float);
    float* hg     = (float*)p;                          p += 4 * NGRAPH * D * sizeof(float);
    int*   counts = (int*)p;                            p += (size_t)n_nodes * sizeof(int);
    size_t zero_bytes = (size_t)(p - (unsigned char*)d_ws);
    int*   rowptr = (int*)p;                            p += ((size_t)n_nodes + 1) * sizeof(int);
    int*   blocksums = (int*)p;                         p += 64 * sizeof(int);
    float* ctxgW  = (float*)p;                          p += NGRAPH * D * sizeof(float);
    int*   srcs   = (int*)p;                            p += (size_t)n_edges * sizeof(int);
    p = (unsigned char*)(((uintptr_t)p + 15) & ~(uintptr_t)15);
    unsigned short* Hbf = (unsigned short*)p;           p += (size_t)n_nodes * D * sizeof(short);
    unsigned short* Xbf = (unsigned short*)p;           p += (size_t)n_nodes * D * sizeof(short);
    unsigned short* WTb = (unsigned short*)p;           p += 3 * D * D * sizeof(short);

    const int pool_blocks = (n_nodes + POOL_CHUNK - 1) / POOL_CHUNK;
    const int mm_blocks = (n_nodes + 63) / 64;
    const int scan_blocks = (n_nodes + SCAN_CHUNK - 1) / SCAN_CHUNK;
    const int gather_blocks = (n_nodes + GNODES - 1) / GNODES;
    const int n4 = n_nodes * D / 4;

    // ---- one-shot zeroing (ctx + hg[0..3] + counts are contiguous) ----
    hipMemsetAsync(ctx, 0, zero_bytes, stream);

    // ---- CSR build ----
    hist_kernel<<<1024, 256, 0, stream>>>(dst, counts, n_edges);
    scanA_kernel<<<scan_blocks, SCAN_TPB, 0, stream>>>(counts, rowptr, blocksums, n_nodes);
    scanC_kernel<<<scan_blocks, SCAN_TPB, 0, stream>>>(rowptr, counts, blocksums, n_nodes);
    fill_kernel<<<1024, 256, 0, stream>>>(src, dst, counts, srcs, n_edges);

    // ---- dtype prep ----
    conv_kernel<<<2048, 256, 0, stream>>>((const float4*)inputs, (ushort4*)Hbf, n4);
    wconv_kernel<<<dim3(64, 3), 256, 0, stream>>>(Wmat[0], Wmat[1], Wmat[2], WTb);

    // ---- pools: init->ctx, lead->ctx, inputs->hg0 ----
    pool3_kernel<<<dim3(pool_blocks, 3), D, 0, stream>>>(
        init_feats, init_gids, ctx, lead_feats, lead_gids, ctx,
        inputs, graph_ids, hg, n_nodes);

    for (int layer = 0; layer < 3; ++layer) {
        float* hgL = hg + layer * NGRAPH * D;
        ctxw_kernel<<<NGRAPH, D, 0, stream>>>(hgL, ctx, Wmat[layer], bvec[layer], ctxgW);
        mm_mfma<<<mm_blocks, 256, 0, stream>>>(Hbf, WTb + layer * D * D, Xbf, n_nodes);
        gather_kernel<<<gather_blocks, 256, 0, stream>>>(Xbf, rowptr, srcs, graph_ids,
                                                         (const float4*)ctxgW, Hbf, n_nodes);
        pool_b16_kernel<<<pool_blocks, D, 0, stream>>>(Hbf, graph_ids,
                                                       hg + (layer + 1) * NGRAPH * D, n_nodes);
    }

    // ---- head ----
    head_kernel<<<NGRAPH, D, 0, stream>>>(hg + 3 * NGRAPH * D, fc1W, fc1b, fc2W, fc2b, out);
}